// Round 11
// baseline (114.507 us; speedup 1.0000x reference)
//
#include <hip/hip_runtime.h>
#include <hip/hip_bf16.h>
#include <math.h>

typedef float  float4v __attribute__((ext_vector_type(4)));
typedef float  f32x16  __attribute__((ext_vector_type(16)));
typedef _Float16 half8  __attribute__((ext_vector_type(8)));
typedef _Float16 h2v    __attribute__((ext_vector_type(2)));
typedef __fp16  fp16x2 __attribute__((ext_vector_type(2)));
typedef unsigned int   uN4 __attribute__((ext_vector_type(4)));
typedef unsigned int   uint2v __attribute__((ext_vector_type(2)));
typedef unsigned short us4 __attribute__((ext_vector_type(4)));

constexpr int Cc = 256;    // C_IN
constexpr int Ci = 128;    // C_INT
constexpr int Nn = 4096;   // H*W
constexpr float LOG2E = 1.4426950408889634f;

// ws layout (ushort units). All fp16 unless noted.
// V and Q stored FRAGMENT-TILED (granule = 16B = 8 halves):
//   V_tiled[b][mt(128)][slot(16)= kt*2+g][m_in(32)][e(8)]
//   Q_tiled[b][mt(128)][s(4) = kt2*2+g][o(128)][e(8)]
constexpr size_t KT  = 0;          // K [b][n][o] (4 MB) — log2e-scaled
constexpr size_t VT  = 2097152;    // V tiled (4 MB)
constexpr size_t QT  = 4194304;    // Q tiled (4 MB)
constexpr size_t OB  = 6291456;    // O partials [mh][b][n][o], 4 x 4 MB
constexpr size_t OSZ = 2097152;
constexpr size_t STAT_BYTE = 29360128;  // Mst[16][4096], Lst[16][4096] f32
constexpr size_t WH  = 14942208;   // stacked weights fp16 [384][256]
constexpr size_t WOH = 15040512;   // w_w fp16 [256][128]

__device__ __forceinline__ f32x16 zero16() {
  f32x16 z;
  #pragma unroll
  for (int r = 0; r < 16; ++r) z[r] = 0.0f;
  return z;
}
__device__ __forceinline__ unsigned pkf(float x, float y) {
  union { fp16x2 h; unsigned u; } c;
  c.h = __builtin_amdgcn_cvt_pkrtz(x, y);
  return c.u;
}
__device__ __forceinline__ f32x16 mfmaf16(half8 a, half8 b, f32x16 c) {
  return __builtin_amdgcn_mfma_f32_32x32x16_f16(a, b, c, 0, 0, 0);
}
__device__ __forceinline__ float h2f(unsigned short u) {
  union { unsigned short u; _Float16 h; } c; c.u = u; return (float)c.h;
}
__device__ __forceinline__ unsigned short f2h(float x) {
  union { _Float16 h; unsigned short u; } c; c.h = (_Float16)x; return c.u;
}
__device__ __forceinline__ unsigned pkfma(unsigned a, unsigned b, unsigned c) {
  union { unsigned u; h2v h; } A, B, C, R;
  A.u = a; B.u = b; C.u = c;
  R.h = A.h * B.h + C.h;
  return R.u;
}
__device__ __forceinline__ unsigned pkmul(unsigned a, unsigned b) {
  union { unsigned u; h2v h; } A, B, R;
  A.u = a; B.u = b;
  R.h = A.h * B.h;
  return R.u;
}
__device__ __forceinline__ float ex2(float x) {
  float r;
  asm volatile("v_exp_f32 %0, %1\n\ts_nop 0" : "=v"(r) : "v"(x));
  return r;
}
__device__ __forceinline__ void gload16(const unsigned short* src, unsigned char* lds) {
  __builtin_amdgcn_global_load_lds(
      (const __attribute__((address_space(1))) unsigned int*)src,
      (__attribute__((address_space(3))) unsigned int*)lds,
      16, 0, 0);
}

// PV A-fragment from this lane's 8 P-values via permlane32_swap (T12).
__device__ __forceinline__ half8 pfrag2(float p0, float p1, float p2, float p3,
                                        float p4, float p5, float p6, float p7) {
  unsigned a0 = pkf(p0, p1), a1 = pkf(p2, p3);
  unsigned b0 = pkf(p4, p5), b1 = pkf(p6, p7);
  uint2v rA = __builtin_amdgcn_permlane32_swap(a0, b0, false, false);
  uint2v rB = __builtin_amdgcn_permlane32_swap(a1, b1, false, false);
  union { unsigned u[4]; half8 h; } r;
  r.u[0] = rA.x; r.u[1] = rB.x; r.u[2] = rA.y; r.u[3] = rB.y;
  return r.h;
}

// ---------------------------------------------------------------------------
// Kernel 0: prep_w — weight conversion only (theta scaled by log2e).
// Grid 128 x 256 thr.
// ---------------------------------------------------------------------------
__global__ __launch_bounds__(256)
void prep_w_kernel(const float* __restrict__ tw, const float* __restrict__ pw,
                   const float* __restrict__ gw, const float* __restrict__ ww,
                   unsigned short* __restrict__ ws16) {
  int i = blockIdx.x*1024 + threadIdx.x*4;
  const float* src; unsigned short* dst; float sc = 1.0f;
  if (i < 32768)      { src = tw + i;           dst = ws16 + WH + i; sc = LOG2E; }
  else if (i < 65536) { src = pw + (i - 32768); dst = ws16 + WH + i; }
  else if (i < 98304) { src = gw + (i - 65536); dst = ws16 + WH + i; }
  else                { src = ww + (i - 98304); dst = ws16 + WOH + (i - 98304); }
  float4v v = *(const float4v*)src;
  us4 o;
  #pragma unroll
  for (int k = 0; k < 4; ++k) o[k] = f2h(v[k] * sc);
  *(us4*)dst = o;
}

// ---------------------------------------------------------------------------
// Kernel 1: proj2 — fused projections, x read DIRECTLY (no x^T staging).
// Grid 256 = b(4) x nt(64). 128 thr (2 waves x 32 rows). Per wave: build
// xfrags[16] once from x (8 coalesced f32 loads + pack per kt), reuse for
// all three projections. Stores identical to previous proj.
// ---------------------------------------------------------------------------
__global__ __launch_bounds__(128)
void proj_kernel(const float* __restrict__ x,
                 const float* __restrict__ tb, const float* __restrict__ pb,
                 const float* __restrict__ gb, unsigned short* __restrict__ ws16) {
  const int L = blockIdx.x;          // 256
  const int b = L & 3, nt = L >> 2;  // nt 0..63
  const int n0 = nt * 64;
  const int tid = threadIdx.x, w = tid >> 6, lane = tid & 63;
  const int l31 = lane & 31, g = lane >> 5;
  const int n = n0 + w*32 + l31;

  // ---- build x fragments: xfrags[kt] elements = x[b][kt*16+g*8+e][n] ----
  half8 xfrags[16];
  const float* xb = x + (((size_t)(b*256)) << 12) + n;
  #pragma unroll
  for (int kt = 0; kt < 16; ++kt) {
    float f[8];
    #pragma unroll
    for (int e = 0; e < 8; ++e)
      f[e] = xb[((size_t)(kt*16 + g*8 + e)) << 12];
    union { unsigned u[4]; half8 h; } r;
    #pragma unroll
    for (int i = 0; i < 4; ++i) r.u[i] = pkf(f[2*i], f[2*i+1]);
    xfrags[kt] = r.h;
  }

  const unsigned short* wh = ws16 + WH + g*8;

  // ---- p = 0 (theta -> K [b][n][o], log2e pre-scaled weights) ----
  {
    f32x16 acc[4];
    #pragma unroll
    for (int ot = 0; ot < 4; ++ot) acc[ot] = zero16();
    #pragma unroll
    for (int kt = 0; kt < 16; ++kt) {
      #pragma unroll
      for (int ot = 0; ot < 4; ++ot) {
        half8 wf = *(const half8*)(wh + (((size_t)(ot*32 + l31)) << 8) + kt*16);
        acc[ot] = mfmaf16(xfrags[kt], wf, acc[ot]);   // D[n][o]
      }
    }
    unsigned short* outb = ws16 + KT + (((size_t)(b*4096 + n0 + w*32)) << 7);
    #pragma unroll
    for (int ot = 0; ot < 4; ++ot) {
      float bv = tb[ot*32 + l31] * LOG2E;
      #pragma unroll
      for (int r = 0; r < 16; ++r) {
        int row = (r & 3) + 8*(r >> 2) + 4*g;
        outb[(((size_t)row) << 7) + ot*32 + l31] = f2h(acc[ot][r] + bv);
      }
    }
  }

  // ---- p = 1 (phi -> V tiled) ----
  {
    f32x16 acc[4];
    #pragma unroll
    for (int ot = 0; ot < 4; ++ot) acc[ot] = zero16();
    #pragma unroll
    for (int kt = 0; kt < 16; ++kt) {
      #pragma unroll
      for (int ot = 0; ot < 4; ++ot) {
        half8 wf = *(const half8*)(wh + 32768 + (((size_t)(ot*32 + l31)) << 8) + kt*16);
        acc[ot] = mfmaf16(xfrags[kt], wf, acc[ot]);   // D[n][o]
      }
    }
    unsigned short* vt = ws16 + VT;
    const size_t mtb = (size_t)(b*128 + nt*2 + w) * 512;
    #pragma unroll
    for (int ot = 0; ot < 4; ++ot) {
      const int o = ot*32 + l31;
      float bv = pb[o];
      const size_t obase = (mtb + (o >> 3)*32)*8 + (o & 7);
      #pragma unroll
      for (int r = 0; r < 16; ++r) {
        int crow = (r & 3) + 8*(r >> 2) + 4*g;
        vt[obase + crow*8] = f2h(acc[ot][r] + bv);
      }
    }
  }

  // ---- p = 2 (g -> Q tiled) ----
  {
    f32x16 acc[4];
    #pragma unroll
    for (int ot = 0; ot < 4; ++ot) acc[ot] = zero16();
    #pragma unroll
    for (int kt = 0; kt < 16; ++kt) {
      #pragma unroll
      for (int ot = 0; ot < 4; ++ot) {
        half8 wf = *(const half8*)(wh + 65536 + (((size_t)(ot*32 + l31)) << 8) + kt*16);
        acc[ot] = mfmaf16(wf, xfrags[kt], acc[ot]);   // D[o][n]
      }
    }
    unsigned short* qt = ws16 + QT;
    const size_t mtb = (size_t)(b*128 + nt*2 + w) * 512;
    const size_t lbase = (mtb + (l31 >> 3)*128)*8 + (l31 & 7);
    #pragma unroll
    for (int ot = 0; ot < 4; ++ot) {
      #pragma unroll
      for (int r = 0; r < 16; ++r) {
        int o = ot*32 + (r & 3) + 8*(r >> 2) + 4*g;
        qt[lbase + o*8] = f2h(acc[ot][r] + gb[o]);
      }
    }
  }
}

// ---------------------------------------------------------------------------
// Kernel 2: flash attention — 2-wave blocks, LDS-shared V/Q (traffic /2),
// double-buffered gload16 staging, one barrier/iter, 4 blocks/CU.
// Grid 1024 = rb(64) x mh(4) x b(4); 128 thr; LDS 32 KB.
// ---------------------------------------------------------------------------
__global__ __launch_bounds__(128, 2)
void attn_kernel(unsigned short* __restrict__ ws16,
                 float* __restrict__ Mst, float* __restrict__ Lst) {
  const int L  = blockIdx.x;            // 1024
  const int b  = L & 3;
  const int mh = (L >> 2) & 3;
  const int rb = L >> 4;                // 0..63
  const int r0 = rb * 64;
  constexpr int NT = 32;
  const int mt0 = b*128 + mh*32;

  const int tid  = threadIdx.x;         // 0..127
  const int w    = tid >> 6;            // 0..1
  const int lane = tid & 63;
  const int l31  = lane & 31;
  const int g    = lane >> 5;

  __shared__ __align__(16) unsigned char smem[32768];
  // V: 0 / 8192 ; Q: 16384 / 24576

  const int nrow = r0 + w*32 + l31;
  half8 kh[8];
  {
    const unsigned short* Kt = ws16 + KT + (((size_t)(b*4096 + nrow)) << 7);
    #pragma unroll
    for (int kt = 0; kt < 8; ++kt)
      kh[kt] = *(const half8*)(Kt + kt*16 + g*8);
  }

  f32x16 acc[4];
  #pragma unroll
  for (int ot = 0; ot < 4; ++ot) acc[ot] = zero16();
  float mreg = -INFINITY, lreg = 0.0f;

  const unsigned short* vbase = ws16 + VT + (size_t)mt0*4096;
  const unsigned short* qbase = ws16 + QT + (size_t)mt0*4096;

  // prologue: stage tile 0 into buffers 0
  #pragma unroll
  for (int k = 0; k < 4; ++k) {
    const int gi = tid + (k << 7);      // 0..511
    gload16(vbase + gi*8, smem + gi*16);
    gload16(qbase + gi*8, smem + 16384 + gi*16);
  }
  __syncthreads();

  #pragma unroll 1
  for (int t = 0; t < NT; ++t) {
    unsigned char* vb = smem + ((t & 1) << 13);
    unsigned char* qb = smem + 16384 + ((t & 1) << 13);

    if (t + 1 < NT) {                    // stage next tile into other buffers
      const unsigned short* vs = vbase + (size_t)(t+1)*4096;
      const unsigned short* qs = qbase + (size_t)(t+1)*4096;
      unsigned char* nvb = smem + (((t & 1) ^ 1) << 13);
      unsigned char* nqb = smem + 16384 + (((t & 1) ^ 1) << 13);
      #pragma unroll
      for (int k = 0; k < 4; ++k) {
        const int gi = tid + (k << 7);
        gload16(vs + gi*8, nvb + gi*16);
        gload16(qs + gi*8, nqb + gi*16);
      }
    }

    // ---- QK^T (log2 domain): two independent 4-deep chains ----
    f32x16 cE = zero16(), cO = zero16();
    __builtin_amdgcn_s_setprio(1);
    #pragma unroll
    for (int kt = 0; kt < 4; ++kt) {
      half8 v0 = *(const half8*)(vb + (((2*kt)*2   + g)*32 + l31)*16);
      half8 v1 = *(const half8*)(vb + (((2*kt+1)*2 + g)*32 + l31)*16);
      cE = mfmaf16(v0, kh[2*kt],   cE);
      cO = mfmaf16(v1, kh[2*kt+1], cO);
    }
    __builtin_amdgcn_s_setprio(0);
    f32x16 c0 = cE + cO;

    // ---- softmax: lane owns row n=l31-half, tree reduce ----
    float a4[8];
    #pragma unroll
    for (int i = 0; i < 8; ++i) a4[i] = fmaxf(c0[i], c0[i+8]);
    #pragma unroll
    for (int i = 0; i < 4; ++i) a4[i] = fmaxf(a4[i], a4[i+4]);
    float tm = fmaxf(fmaxf(a4[0], a4[1]), fmaxf(a4[2], a4[3]));
    tm = fmaxf(tm, __shfl_xor(tm, 32));

    float f = 1.0f;
    if (__any(tm > mreg + 11.0f)) {       // T13 defer-max (log2 units)
      float mn = fmaxf(mreg, tm);
      f = ex2(mreg - mn);
      mreg = mn;
      #pragma unroll
      for (int r = 0; r < 16; ++r) {
        const int nl = (r & 3) + 8*(r >> 2) + 4*g;
        float fr = __shfl(f, nl);
        acc[0][r] *= fr; acc[1][r] *= fr; acc[2][r] *= fr; acc[3][r] *= fr;
      }
    }
    #pragma unroll
    for (int r = 0; r < 16; ++r) c0[r] = ex2(c0[r] - mreg);
    float sm[8];
    #pragma unroll
    for (int i = 0; i < 8; ++i) sm[i] = c0[i] + c0[i+8];
    #pragma unroll
    for (int i = 0; i < 4; ++i) sm[i] += sm[i+4];
    float ts = (sm[0] + sm[1]) + (sm[2] + sm[3]);
    ts += __shfl_xor(ts, 32);
    lreg = lreg * f + ts;

    // ---- P -> A-fragments (in-register) ----
    half8 pfr0 = pfrag2(c0[0],c0[1],c0[2],c0[3],c0[4],c0[5],c0[6],c0[7]);
    half8 pfr1 = pfrag2(c0[8],c0[9],c0[10],c0[11],c0[12],c0[13],c0[14],c0[15]);

    // ---- PV from LDS Q fragments ----
    __builtin_amdgcn_s_setprio(1);
    #pragma unroll
    for (int ot = 0; ot < 4; ++ot) {
      half8 qf0 = *(const half8*)(qb + ((0*2 + g)*128 + ot*32 + l31)*16);
      half8 qf1 = *(const half8*)(qb + ((1*2 + g)*128 + ot*32 + l31)*16);
      acc[ot] = mfmaf16(pfr0, qf0, acc[ot]);
      acc[ot] = mfmaf16(pfr1, qf1, acc[ot]);
    }
    __builtin_amdgcn_s_setprio(0);

    __syncthreads();                     // DMA for t+1 drained; reads done
  }

  // epilogue: normalized fp16 partial -> OB[mh][b][n][o]
  unsigned short* Ob = ws16 + OB + (size_t)mh*OSZ + (((size_t)(b*4096)) << 7);
  const float linv_own = 1.0f / lreg;
  #pragma unroll
  for (int r = 0; r < 16; ++r) {
    const int nl = (r & 3) + 8*(r >> 2) + 4*g;
    const float linv = __shfl(linv_own, nl);
    const size_t nb = ((size_t)(r0 + w*32 + nl)) << 7;
    #pragma unroll
    for (int ot = 0; ot < 4; ++ot) {
      const int o_ = ot*32 + l31;
      Ob[nb + o_] = f2h(acc[ot][r] * linv);
    }
  }
  if (lane < 32) {
    const int n_ = r0 + w*32 + l31;
    Mst[((mh*4 + b) << 12) + n_] = mreg;   // log2 domain
    Lst[((mh*4 + b) << 12) + n_] = lreg;
  }
}

// ---------------------------------------------------------------------------
// Kernel 3: out projection via MFMA with fused 4-partial merge (unchanged).
// ---------------------------------------------------------------------------
__global__ __launch_bounds__(256)
void out_kernel(const float* __restrict__ x, const float* __restrict__ wb,
                const unsigned short* __restrict__ ws16,
                const float* __restrict__ Mst, const float* __restrict__ Lst,
                float* __restrict__ out) {
  const int L = blockIdx.x;            // 256
  const int b = L & 3, nt = L >> 2;
  const int n0 = nt * 64;
  const int tid = threadIdx.x, w = tid >> 6, lane = tid & 63;
  const int l31 = lane & 31, g = lane >> 5;
  const int nsub = w & 1, chalf = w >> 1;

  __shared__ float cs[4][64];
  if (tid < 64) {
    const int n_ = n0 + tid;
    float m0 = Mst[((0*4+b) << 12) + n_], l0 = Lst[((0*4+b) << 12) + n_];
    float m1 = Mst[((1*4+b) << 12) + n_], l1 = Lst[((1*4+b) << 12) + n_];
    float m2 = Mst[((2*4+b) << 12) + n_], l2 = Lst[((2*4+b) << 12) + n_];
    float m3 = Mst[((3*4+b) << 12) + n_], l3 = Lst[((3*4+b) << 12) + n_];
    float M = fmaxf(fmaxf(m0, m1), fmaxf(m2, m3));
    float w0 = l0 * exp2f(m0 - M);       // stats are log2-domain
    float w1 = l1 * exp2f(m1 - M);
    float w2 = l2 * exp2f(m2 - M);
    float w3 = l3 * exp2f(m3 - M);
    float inv = 1.0f / (w0 + w1 + w2 + w3);
    cs[0][tid] = w0*inv; cs[1][tid] = w1*inv; cs[2][tid] = w2*inv; cs[3][tid] = w3*inv;
  }
  __syncthreads();

  const int n_lane = n0 + nsub*32 + l31;
  unsigned csh[4];
  #pragma unroll
  for (int p = 0; p < 4; ++p) {
    float c = cs[p][nsub*32 + l31];
    csh[p] = pkf(c, c);
  }

  f32x16 acc[4];
  #pragma unroll
  for (int ct = 0; ct < 4; ++ct) acc[ct] = zero16();

  const unsigned short* ob = ws16 + OB + (((size_t)(b*4096 + n_lane)) << 7) + g*8;
  const unsigned short* wrow = ws16 + WOH + g*8;

  #pragma unroll
  for (int kt = 0; kt < 8; ++kt) {
    uN4 u0 = *(const uN4*)(ob + kt*16);
    uN4 u1 = *(const uN4*)(ob + OSZ + kt*16);
    uN4 u2 = *(const uN4*)(ob + 2*OSZ + kt*16);
    uN4 u3 = *(const uN4*)(ob + 3*OSZ + kt*16);
    union { uN4 u; half8 h; } m;
    #pragma unroll
    for (int i = 0; i < 4; ++i)
      m.u[i] = pkfma(u0[i], csh[0],
               pkfma(u1[i], csh[1],
               pkfma(u2[i], csh[2], pkmul(u3[i], csh[3]))));
    #pragma unroll
    for (int ct = 0; ct < 4; ++ct) {
      half8 wf = *(const half8*)(wrow + (((size_t)((chalf*4 + ct)*32 + l31)) << 7) + kt*16);
      acc[ct] = mfmaf16(wf, m.h, acc[ct]);   // D[c][n]
    }
  }

  #pragma unroll
  for (int ct = 0; ct < 4; ++ct) {
    #pragma unroll
    for (int r = 0; r < 16; ++r) {
      const int c = (chalf*4 + ct)*32 + (r & 3) + 8*(r >> 2) + 4*g;
      const size_t off = ((size_t)(b*256 + c) << 12) + n_lane;
      out[off] = acc[ct][r] + wb[c] + x[off];
    }
  }
}

extern "C" void kernel_launch(void* const* d_in, const int* in_sizes, int n_in,
                              void* d_out, int out_size, void* d_ws, size_t ws_size,
                              hipStream_t stream) {
  const float* x  = (const float*)d_in[0];
  const float* tw = (const float*)d_in[1];
  const float* tb = (const float*)d_in[2];
  const float* pw = (const float*)d_in[3];
  const float* pb = (const float*)d_in[4];
  const float* gw = (const float*)d_in[5];
  const float* gb = (const float*)d_in[6];
  const float* ww = (const float*)d_in[7];
  const float* wbb= (const float*)d_in[8];

  unsigned short* ws16 = (unsigned short*)d_ws;
  float* Mst = (float*)((char*)d_ws + STAT_BYTE);
  float* Lst = Mst + 16*4096;
  float* out = (float*)d_out;

  if (ws_size < 33554432u) return;

  prep_w_kernel<<<128, 256, 0, stream>>>(tw, pw, gw, ww, ws16);
  proj_kernel<<<256, 128, 0, stream>>>(x, tb, pb, gb, ws16);
  attn_kernel<<<1024, 128, 0, stream>>>(ws16, Mst, Lst);
  out_kernel<<<256, 256, 0, stream>>>(x, wbb, ws16, Mst, Lst, out);
}

// Round 12
// 100.818 us; speedup vs baseline: 1.1358x; 1.1358x over previous
//
#include <hip/hip_runtime.h>
#include <hip/hip_bf16.h>
#include <math.h>

typedef float  float4v __attribute__((ext_vector_type(4)));
typedef float  f32x16  __attribute__((ext_vector_type(16)));
typedef _Float16 half8  __attribute__((ext_vector_type(8)));
typedef _Float16 h2v    __attribute__((ext_vector_type(2)));
typedef __fp16  fp16x2 __attribute__((ext_vector_type(2)));
typedef unsigned int   uN4 __attribute__((ext_vector_type(4)));
typedef unsigned int   uint2v __attribute__((ext_vector_type(2)));
typedef unsigned short us4 __attribute__((ext_vector_type(4)));

constexpr int Cc = 256;    // C_IN
constexpr int Ci = 128;    // C_INT
constexpr int Nn = 4096;   // H*W
constexpr float LOG2E = 1.4426950408889634f;

// ws layout (ushort units). All fp16 unless noted.
// V and Q stored FRAGMENT-TILED (granule = 16B = 8 halves):
//   V_tiled[b][mt(128)][slot(16)= kt*2+g][m_in(32)][e(8)]
//   Q_tiled[b][mt(128)][s(4) = kt2*2+g][o(128)][e(8)]
constexpr size_t KT  = 0;          // K [b][n][o] (4 MB) — log2e-scaled
constexpr size_t VT  = 2097152;    // V tiled (4 MB)
constexpr size_t QT  = 4194304;    // Q tiled (4 MB)
constexpr size_t OB  = 6291456;    // O partials [mh][b][n][o], 4 x 4 MB
constexpr size_t OSZ = 2097152;
constexpr size_t STAT_BYTE = 29360128;  // Mst[16][4096], Lst[16][4096] f32
constexpr size_t WH  = 14942208;   // stacked weights fp16 [384][256]
constexpr size_t WOH = 15040512;   // w_w fp16 [256][128]

__device__ __forceinline__ f32x16 zero16() {
  f32x16 z;
  #pragma unroll
  for (int r = 0; r < 16; ++r) z[r] = 0.0f;
  return z;
}
__device__ __forceinline__ unsigned pkf(float x, float y) {
  union { fp16x2 h; unsigned u; } c;
  c.h = __builtin_amdgcn_cvt_pkrtz(x, y);
  return c.u;
}
__device__ __forceinline__ f32x16 mfmaf16(half8 a, half8 b, f32x16 c) {
  return __builtin_amdgcn_mfma_f32_32x32x16_f16(a, b, c, 0, 0, 0);
}
__device__ __forceinline__ float h2f(unsigned short u) {
  union { unsigned short u; _Float16 h; } c; c.u = u; return (float)c.h;
}
__device__ __forceinline__ unsigned short f2h(float x) {
  union { _Float16 h; unsigned short u; } c; c.h = (_Float16)x; return c.u;
}
__device__ __forceinline__ unsigned pkfma(unsigned a, unsigned b, unsigned c) {
  union { unsigned u; h2v h; } A, B, C, R;
  A.u = a; B.u = b; C.u = c;
  R.h = A.h * B.h + C.h;
  return R.u;
}
__device__ __forceinline__ unsigned pkmul(unsigned a, unsigned b) {
  union { unsigned u; h2v h; } A, B, R;
  A.u = a; B.u = b;
  R.h = A.h * B.h;
  return R.u;
}
__device__ __forceinline__ float ex2(float x) {
  float r;
  asm volatile("v_exp_f32 %0, %1\n\ts_nop 0" : "=v"(r) : "v"(x));
  return r;
}
// cross-half (lane ^ 32) reduce via permlane32_swap: returns {own, other}
// in the two words; max/add of the pair is the 64-lane half-merge. ~VALU
// cost, replaces ds_bpermute __shfl_xor(x, 32) on the critical path.
__device__ __forceinline__ float red32_max(float x) {
  union { float f; unsigned u; } a; a.f = x;
  uint2v r = __builtin_amdgcn_permlane32_swap(a.u, a.u, false, false);
  union { unsigned u; float f; } p, q;
  p.u = r.x; q.u = r.y;
  return fmaxf(p.f, q.f);
}
__device__ __forceinline__ float red32_sum(float x) {
  union { float f; unsigned u; } a; a.f = x;
  uint2v r = __builtin_amdgcn_permlane32_swap(a.u, a.u, false, false);
  union { unsigned u; float f; } p, q;
  p.u = r.x; q.u = r.y;
  return p.f + q.f;
}

// PV A-fragment from this lane's 8 P-values via permlane32_swap (T12).
__device__ __forceinline__ half8 pfrag2(float p0, float p1, float p2, float p3,
                                        float p4, float p5, float p6, float p7) {
  unsigned a0 = pkf(p0, p1), a1 = pkf(p2, p3);
  unsigned b0 = pkf(p4, p5), b1 = pkf(p6, p7);
  uint2v rA = __builtin_amdgcn_permlane32_swap(a0, b0, false, false);
  uint2v rB = __builtin_amdgcn_permlane32_swap(a1, b1, false, false);
  union { unsigned u[4]; half8 h; } r;
  r.u[0] = rA.x; r.u[1] = rB.x; r.u[2] = rA.y; r.u[3] = rB.y;
  return r.h;
}

// ---------------------------------------------------------------------------
// Kernel 0: prep_w — weight conversion only (theta scaled by log2e).
// Grid 128 x 256 thr.
// ---------------------------------------------------------------------------
__global__ __launch_bounds__(256)
void prep_w_kernel(const float* __restrict__ tw, const float* __restrict__ pw,
                   const float* __restrict__ gw, const float* __restrict__ ww,
                   unsigned short* __restrict__ ws16) {
  int i = blockIdx.x*1024 + threadIdx.x*4;
  const float* src; unsigned short* dst; float sc = 1.0f;
  if (i < 32768)      { src = tw + i;           dst = ws16 + WH + i; sc = LOG2E; }
  else if (i < 65536) { src = pw + (i - 32768); dst = ws16 + WH + i; }
  else if (i < 98304) { src = gw + (i - 65536); dst = ws16 + WH + i; }
  else                { src = ww + (i - 98304); dst = ws16 + WOH + (i - 98304); }
  float4v v = *(const float4v*)src;
  us4 o;
  #pragma unroll
  for (int k = 0; k < 4; ++k) o[k] = f2h(v[k] * sc);
  *(us4*)dst = o;
}

// ---------------------------------------------------------------------------
// Kernel 1: projections via MFMA, x read DIRECTLY from global (no staging).
// 384 blocks: p(3) x b(4) x nt(32); 256 thr = 4 waves x 32 rows (R10 shape).
// xfrags[16] built from 128 coalesced f32 loads; A/B fragment lane layouts
// are identical so the same xfrags serve D[n][o] (p<2) and D[o][n] (p=2).
// ---------------------------------------------------------------------------
__global__ __launch_bounds__(256)
void proj_kernel(const float* __restrict__ x,
                 const float* __restrict__ tb, const float* __restrict__ pb,
                 const float* __restrict__ gb, unsigned short* __restrict__ ws16) {
  const int L = blockIdx.x;          // 384
  const int p = L >> 7;              // 0=K,1=V,2=Q
  const int rem = L & 127;
  const int b = rem & 3, nt = rem >> 2;
  const int n0 = nt * 128;
  const int tid = threadIdx.x, w = tid >> 6, lane = tid & 63;
  const int l31 = lane & 31, g = lane >> 5;
  const int n = n0 + w*32 + l31;

  // build x fragments: xfrags[kt] elems = x[b][kt*16+g*8+e][n], e=0..7
  half8 xfrags[16];
  {
    const float* xb = x + (((size_t)(b*256 + g*8)) << 12) + n;
    #pragma unroll
    for (int kt = 0; kt < 16; ++kt) {
      float f[8];
      #pragma unroll
      for (int e = 0; e < 8; ++e)
        f[e] = xb[((size_t)(kt*16 + e)) << 12];
      union { unsigned u[4]; half8 h; } r;
      #pragma unroll
      for (int i = 0; i < 4; ++i) r.u[i] = pkf(f[2*i], f[2*i+1]);
      xfrags[kt] = r.h;
    }
  }

  const unsigned short* wh = ws16 + WH + (size_t)p*32768 + g*8;

  f32x16 acc[4];
  #pragma unroll
  for (int ot = 0; ot < 4; ++ot) acc[ot] = zero16();

  if (p < 2) {
    #pragma unroll
    for (int kt = 0; kt < 16; ++kt) {
      #pragma unroll
      for (int ot = 0; ot < 4; ++ot) {
        half8 wf = *(const half8*)(wh + (((size_t)(ot*32 + l31)) << 8) + kt*16);
        acc[ot] = mfmaf16(xfrags[kt], wf, acc[ot]);   // D[n][o]
      }
    }
    if (p == 0) {
      unsigned short* outb = ws16 + KT + (((size_t)(b*4096 + n0 + w*32)) << 7);
      #pragma unroll
      for (int ot = 0; ot < 4; ++ot) {
        float bv = tb[ot*32 + l31] * LOG2E;
        #pragma unroll
        for (int r = 0; r < 16; ++r) {
          int row = (r & 3) + 8*(r >> 2) + 4*g;
          outb[(((size_t)row) << 7) + ot*32 + l31] = f2h(acc[ot][r] + bv);
        }
      }
    } else {
      unsigned short* vt = ws16 + VT;
      const size_t mtb = (size_t)(b*128 + nt*4 + w) * 512;
      #pragma unroll
      for (int ot = 0; ot < 4; ++ot) {
        const int o = ot*32 + l31;
        float bv = pb[o];
        const size_t obase = (mtb + (o >> 3)*32)*8 + (o & 7);
        #pragma unroll
        for (int r = 0; r < 16; ++r) {
          int crow = (r & 3) + 8*(r >> 2) + 4*g;
          vt[obase + crow*8] = f2h(acc[ot][r] + bv);
        }
      }
    }
  } else {
    #pragma unroll
    for (int kt = 0; kt < 16; ++kt) {
      #pragma unroll
      for (int ot = 0; ot < 4; ++ot) {
        half8 wf = *(const half8*)(wh + (((size_t)(ot*32 + l31)) << 8) + kt*16);
        acc[ot] = mfmaf16(wf, xfrags[kt], acc[ot]);   // D[o][n]
      }
    }
    unsigned short* qt = ws16 + QT;
    const size_t mtb = (size_t)(b*128 + nt*4 + w) * 512;
    const size_t lbase = (mtb + (l31 >> 3)*128)*8 + (l31 & 7);
    #pragma unroll
    for (int ot = 0; ot < 4; ++ot) {
      #pragma unroll
      for (int r = 0; r < 16; ++r) {
        int o = ot*32 + (r & 3) + 8*(r >> 2) + 4*g;
        qt[lbase + o*8] = f2h(acc[ot][r] + gb[o]);
      }
    }
  }
}

// ---------------------------------------------------------------------------
// Kernel 2: flash attention — no LDS/barriers; register rotation with
// V prefetch depth 2 (vA/vB, even/odd unroll) + Q depth 1; permlane32_swap
// reductions. Grid 512 x 256 thr, 2 blocks/CU.
// ---------------------------------------------------------------------------
__device__ __forceinline__ void attn_iter2(
    const unsigned short* __restrict__ vbase,
    const unsigned short* __restrict__ qbase,
    int t, half8 (&vcur)[8], half8 (&qbuf)[8], const half8 (&kh)[8],
    f32x16 (&acc)[4], float& mreg, float& lreg, int l31, int g) {
  // ---- QK^T (log2 domain): two independent 4-deep chains ----
  f32x16 cE = zero16(), cO = zero16();
  __builtin_amdgcn_s_setprio(1);
  #pragma unroll
  for (int kt = 0; kt < 4; ++kt) {
    cE = mfmaf16(vcur[2*kt],   kh[2*kt],   cE);
    cO = mfmaf16(vcur[2*kt+1], kh[2*kt+1], cO);
  }
  __builtin_amdgcn_s_setprio(0);
  f32x16 c0 = cE + cO;

  // ---- overwrite vcur with V(t+2): 2 full iterations of slack ----
  {
    const unsigned short* vs = vbase + (size_t)((t + 2) & 31)*4096;
    #pragma unroll
    for (int kt = 0; kt < 8; ++kt)
      vcur[kt] = *(const half8*)(vs + ((kt*2 + g)*32 + l31)*8);
  }

  // ---- softmax: lane owns row n=l31, tree + permlane half-merge ----
  float a4[8];
  #pragma unroll
  for (int i = 0; i < 8; ++i) a4[i] = fmaxf(c0[i], c0[i+8]);
  #pragma unroll
  for (int i = 0; i < 4; ++i) a4[i] = fmaxf(a4[i], a4[i+4]);
  float tm = fmaxf(fmaxf(a4[0], a4[1]), fmaxf(a4[2], a4[3]));
  tm = red32_max(tm);

  float f = 1.0f;
  if (__any(tm > mreg + 11.0f)) {       // T13 defer-max (log2 units)
    float mn = fmaxf(mreg, tm);
    f = ex2(mreg - mn);
    mreg = mn;
    #pragma unroll
    for (int r = 0; r < 16; ++r) {
      const int nl = (r & 3) + 8*(r >> 2) + 4*g;
      float fr = __shfl(f, nl);
      acc[0][r] *= fr; acc[1][r] *= fr; acc[2][r] *= fr; acc[3][r] *= fr;
    }
  }
  #pragma unroll
  for (int r = 0; r < 16; ++r) c0[r] = ex2(c0[r] - mreg);
  float sm[8];
  #pragma unroll
  for (int i = 0; i < 8; ++i) sm[i] = c0[i] + c0[i+8];
  #pragma unroll
  for (int i = 0; i < 4; ++i) sm[i] += sm[i+4];
  float ts = (sm[0] + sm[1]) + (sm[2] + sm[3]);
  ts = red32_sum(ts);
  lreg = lreg * f + ts;

  // ---- P -> A-fragments (in-register) ----
  half8 pfr0 = pfrag2(c0[0],c0[1],c0[2],c0[3],c0[4],c0[5],c0[6],c0[7]);
  half8 pfr1 = pfrag2(c0[8],c0[9],c0[10],c0[11],c0[12],c0[13],c0[14],c0[15]);

  // ---- PV from qbuf regs (loaded one iteration ago) ----
  __builtin_amdgcn_s_setprio(1);
  #pragma unroll
  for (int ot = 0; ot < 4; ++ot) {
    acc[ot] = mfmaf16(pfr0, qbuf[ot*2+0], acc[ot]);
    acc[ot] = mfmaf16(pfr1, qbuf[ot*2+1], acc[ot]);
  }
  __builtin_amdgcn_s_setprio(0);

  // ---- overwrite qbuf with Q(t+1): next use is QK^T+softmax away ----
  {
    const unsigned short* qs = qbase + (size_t)((t + 1) & 31)*4096;
    #pragma unroll
    for (int ot = 0; ot < 4; ++ot) {
      qbuf[ot*2+0] = *(const half8*)(qs + ((0*2 + g)*128 + ot*32 + l31)*8);
      qbuf[ot*2+1] = *(const half8*)(qs + ((1*2 + g)*128 + ot*32 + l31)*8);
    }
  }
}

__global__ __launch_bounds__(256, 2)
void attn_kernel(unsigned short* __restrict__ ws16,
                 float* __restrict__ Mst, float* __restrict__ Lst) {
  const int L  = blockIdx.x;            // 512
  const int b  = L & 3;
  const int mh = (L >> 2) & 3;
  const int rb = L >> 4;
  const int r0 = rb * 128;
  constexpr int NT = 32;
  const int mt0 = b*128 + mh*32;

  const int tid  = threadIdx.x;
  const int w    = tid >> 6;
  const int lane = tid & 63;
  const int l31  = lane & 31;
  const int g    = lane >> 5;

  const int nrow = r0 + w*32 + l31;
  half8 kh[8];
  {
    const unsigned short* Kt = ws16 + KT + (((size_t)(b*4096 + nrow)) << 7);
    #pragma unroll
    for (int kt = 0; kt < 8; ++kt)
      kh[kt] = *(const half8*)(Kt + kt*16 + g*8);
  }

  f32x16 acc[4];
  #pragma unroll
  for (int ot = 0; ot < 4; ++ot) acc[ot] = zero16();
  float mreg = -INFINITY, lreg = 0.0f;

  const unsigned short* vbase = ws16 + VT + (size_t)mt0*4096;
  const unsigned short* qbase = ws16 + QT + (size_t)mt0*4096;

  half8 vA[8], vB[8], qbuf[8];
  #pragma unroll
  for (int kt = 0; kt < 8; ++kt) {
    vA[kt] = *(const half8*)(vbase +        ((kt*2 + g)*32 + l31)*8);
    vB[kt] = *(const half8*)(vbase + 4096 + ((kt*2 + g)*32 + l31)*8);
  }
  #pragma unroll
  for (int ot = 0; ot < 4; ++ot) {
    qbuf[ot*2+0] = *(const half8*)(qbase + ((0*2 + g)*128 + ot*32 + l31)*8);
    qbuf[ot*2+1] = *(const half8*)(qbase + ((1*2 + g)*128 + ot*32 + l31)*8);
  }

  #pragma unroll 1
  for (int t = 0; t < NT; t += 2) {
    attn_iter2(vbase, qbase, t,     vA, qbuf, kh, acc, mreg, lreg, l31, g);
    attn_iter2(vbase, qbase, t + 1, vB, qbuf, kh, acc, mreg, lreg, l31, g);
  }

  // epilogue: normalized fp16 partial -> OB[mh][b][n][o]
  unsigned short* Ob = ws16 + OB + (size_t)mh*OSZ + (((size_t)(b*4096)) << 7);
  const float linv_own = 1.0f / lreg;
  #pragma unroll
  for (int r = 0; r < 16; ++r) {
    const int nl = (r & 3) + 8*(r >> 2) + 4*g;
    const float linv = __shfl(linv_own, nl);
    const size_t nb = ((size_t)(r0 + w*32 + nl)) << 7;
    #pragma unroll
    for (int ot = 0; ot < 4; ++ot) {
      const int o_ = ot*32 + l31;
      Ob[nb + o_] = f2h(acc[ot][r] * linv);
    }
  }
  if (lane < 32) {
    const int n_ = r0 + w*32 + l31;
    Mst[((mh*4 + b) << 12) + n_] = mreg;   // log2 domain
    Lst[((mh*4 + b) << 12) + n_] = lreg;
  }
}

// ---------------------------------------------------------------------------
// Kernel 3: out projection via MFMA with fused 4-partial merge (unchanged).
// ---------------------------------------------------------------------------
__global__ __launch_bounds__(256)
void out_kernel(const float* __restrict__ x, const float* __restrict__ wb,
                const unsigned short* __restrict__ ws16,
                const float* __restrict__ Mst, const float* __restrict__ Lst,
                float* __restrict__ out) {
  const int L = blockIdx.x;            // 256
  const int b = L & 3, nt = L >> 2;
  const int n0 = nt * 64;
  const int tid = threadIdx.x, w = tid >> 6, lane = tid & 63;
  const int l31 = lane & 31, g = lane >> 5;
  const int nsub = w & 1, chalf = w >> 1;

  __shared__ float cs[4][64];
  if (tid < 64) {
    const int n_ = n0 + tid;
    float m0 = Mst[((0*4+b) << 12) + n_], l0 = Lst[((0*4+b) << 12) + n_];
    float m1 = Mst[((1*4+b) << 12) + n_], l1 = Lst[((1*4+b) << 12) + n_];
    float m2 = Mst[((2*4+b) << 12) + n_], l2 = Lst[((2*4+b) << 12) + n_];
    float m3 = Mst[((3*4+b) << 12) + n_], l3 = Lst[((3*4+b) << 12) + n_];
    float M = fmaxf(fmaxf(m0, m1), fmaxf(m2, m3));
    float w0 = l0 * exp2f(m0 - M);       // stats are log2-domain
    float w1 = l1 * exp2f(m1 - M);
    float w2 = l2 * exp2f(m2 - M);
    float w3 = l3 * exp2f(m3 - M);
    float inv = 1.0f / (w0 + w1 + w2 + w3);
    cs[0][tid] = w0*inv; cs[1][tid] = w1*inv; cs[2][tid] = w2*inv; cs[3][tid] = w3*inv;
  }
  __syncthreads();

  const int n_lane = n0 + nsub*32 + l31;
  unsigned csh[4];
  #pragma unroll
  for (int p = 0; p < 4; ++p) {
    float c = cs[p][nsub*32 + l31];
    csh[p] = pkf(c, c);
  }

  f32x16 acc[4];
  #pragma unroll
  for (int ct = 0; ct < 4; ++ct) acc[ct] = zero16();

  const unsigned short* ob = ws16 + OB + (((size_t)(b*4096 + n_lane)) << 7) + g*8;
  const unsigned short* wrow = ws16 + WOH + g*8;

  #pragma unroll
  for (int kt = 0; kt < 8; ++kt) {
    uN4 u0 = *(const uN4*)(ob + kt*16);
    uN4 u1 = *(const uN4*)(ob + OSZ + kt*16);
    uN4 u2 = *(const uN4*)(ob + 2*OSZ + kt*16);
    uN4 u3 = *(const uN4*)(ob + 3*OSZ + kt*16);
    union { uN4 u; half8 h; } m;
    #pragma unroll
    for (int i = 0; i < 4; ++i)
      m.u[i] = pkfma(u0[i], csh[0],
               pkfma(u1[i], csh[1],
               pkfma(u2[i], csh[2], pkmul(u3[i], csh[3]))));
    #pragma unroll
    for (int ct = 0; ct < 4; ++ct) {
      half8 wf = *(const half8*)(wrow + (((size_t)((chalf*4 + ct)*32 + l31)) << 7) + kt*16);
      acc[ct] = mfmaf16(wf, m.h, acc[ct]);   // D[c][n]
    }
  }

  #pragma unroll
  for (int ct = 0; ct < 4; ++ct) {
    #pragma unroll
    for (int r = 0; r < 16; ++r) {
      const int c = (chalf*4 + ct)*32 + (r & 3) + 8*(r >> 2) + 4*g;
      const size_t off = ((size_t)(b*256 + c) << 12) + n_lane;
      out[off] = acc[ct][r] + wb[c] + x[off];
    }
  }
}

extern "C" void kernel_launch(void* const* d_in, const int* in_sizes, int n_in,
                              void* d_out, int out_size, void* d_ws, size_t ws_size,
                              hipStream_t stream) {
  const float* x  = (const float*)d_in[0];
  const float* tw = (const float*)d_in[1];
  const float* tb = (const float*)d_in[2];
  const float* pw = (const float*)d_in[3];
  const float* pb = (const float*)d_in[4];
  const float* gw = (const float*)d_in[5];
  const float* gb = (const float*)d_in[6];
  const float* ww = (const float*)d_in[7];
  const float* wbb= (const float*)d_in[8];

  unsigned short* ws16 = (unsigned short*)d_ws;
  float* Mst = (float*)((char*)d_ws + STAT_BYTE);
  float* Lst = Mst + 16*4096;
  float* out = (float*)d_out;

  if (ws_size < 33554432u) return;

  prep_w_kernel<<<128, 256, 0, stream>>>(tw, pw, gw, ww, ws16);
  proj_kernel<<<384, 256, 0, stream>>>(x, tb, pb, gb, ws16);
  attn_kernel<<<512, 256, 0, stream>>>(ws16, Mst, Lst);
  out_kernel<<<256, 256, 0, stream>>>(x, wbb, ws16, Mst, Lst, out);
}

// Round 13
// 96.057 us; speedup vs baseline: 1.1921x; 1.0496x over previous
//
#include <hip/hip_runtime.h>
#include <hip/hip_bf16.h>
#include <math.h>

typedef float  float4v __attribute__((ext_vector_type(4)));
typedef float  f32x16  __attribute__((ext_vector_type(16)));
typedef _Float16 half8  __attribute__((ext_vector_type(8)));
typedef _Float16 h2v    __attribute__((ext_vector_type(2)));
typedef __fp16  fp16x2 __attribute__((ext_vector_type(2)));
typedef unsigned int   uN4 __attribute__((ext_vector_type(4)));
typedef unsigned int   uint2v __attribute__((ext_vector_type(2)));
typedef unsigned short us4 __attribute__((ext_vector_type(4)));

constexpr int Cc = 256;    // C_IN
constexpr int Ci = 128;    // C_INT
constexpr int Nn = 4096;   // H*W
constexpr float LOG2E = 1.4426950408889634f;

// ws layout (ushort units). All fp16 unless noted.
// V and Q stored FRAGMENT-TILED (granule = 16B = 8 halves):
//   V_tiled[b][mt(128)][slot(16)= kt*2+g][m_in(32)][e(8)]
//   Q_tiled[b][mt(128)][s(4) = kt2*2+g][o(128)][e(8)]
constexpr size_t KT  = 0;          // K [b][n][o] (4 MB) — log2e-scaled
constexpr size_t VT  = 2097152;    // V tiled (4 MB)
constexpr size_t QT  = 4194304;    // Q tiled (4 MB)
constexpr size_t OB  = 6291456;    // O partials [mh][b][n][o], 4 x 4 MB
constexpr size_t OSZ = 2097152;
constexpr size_t XH  = 6291456;    // x^T [b][n][c] fp16 (8 MB) — ALIASES OB[0..1]
constexpr size_t STAT_BYTE = 29360128;  // Mst[16][4096], Lst[16][4096] f32
constexpr size_t WH  = 14942208;   // stacked weights fp16 [384][256]
constexpr size_t WOH = 15040512;   // w_w fp16 [256][128]

__device__ __forceinline__ f32x16 zero16() {
  f32x16 z;
  #pragma unroll
  for (int r = 0; r < 16; ++r) z[r] = 0.0f;
  return z;
}
__device__ __forceinline__ unsigned pkf(float x, float y) {
  union { fp16x2 h; unsigned u; } c;
  c.h = __builtin_amdgcn_cvt_pkrtz(x, y);
  return c.u;
}
__device__ __forceinline__ f32x16 mfmaf16(half8 a, half8 b, f32x16 c) {
  return __builtin_amdgcn_mfma_f32_32x32x16_f16(a, b, c, 0, 0, 0);
}
__device__ __forceinline__ float h2f(unsigned short u) {
  union { unsigned short u; _Float16 h; } c; c.u = u; return (float)c.h;
}
__device__ __forceinline__ unsigned short f2h(float x) {
  union { _Float16 h; unsigned short u; } c; c.h = (_Float16)x; return c.u;
}
__device__ __forceinline__ unsigned pkfma(unsigned a, unsigned b, unsigned c) {
  union { unsigned u; h2v h; } A, B, C, R;
  A.u = a; B.u = b; C.u = c;
  R.h = A.h * B.h + C.h;
  return R.u;
}
__device__ __forceinline__ unsigned pkmul(unsigned a, unsigned b) {
  union { unsigned u; h2v h; } A, B, R;
  A.u = a; B.u = b;
  R.h = A.h * B.h;
  return R.u;
}
__device__ __forceinline__ float ex2(float x) {
  float r;
  asm volatile("v_exp_f32 %0, %1\n\ts_nop 0" : "=v"(r) : "v"(x));
  return r;
}
__device__ __forceinline__ void gload16(const unsigned short* src, unsigned char* lds) {
  __builtin_amdgcn_global_load_lds(
      (const __attribute__((address_space(1))) unsigned int*)src,
      (__attribute__((address_space(3))) unsigned int*)lds,
      16, 0, 0);
}

// PV A-fragment from this lane's 8 P-values via permlane32_swap (T12).
__device__ __forceinline__ half8 pfrag2(float p0, float p1, float p2, float p3,
                                        float p4, float p5, float p6, float p7) {
  unsigned a0 = pkf(p0, p1), a1 = pkf(p2, p3);
  unsigned b0 = pkf(p4, p5), b1 = pkf(p6, p7);
  uint2v rA = __builtin_amdgcn_permlane32_swap(a0, b0, false, false);
  uint2v rB = __builtin_amdgcn_permlane32_swap(a1, b1, false, false);
  union { unsigned u[4]; half8 h; } r;
  r.u[0] = rA.x; r.u[1] = rB.x; r.u[2] = rA.y; r.u[3] = rB.y;
  return r.h;
}

// ---------------------------------------------------------------------------
// Kernel 0: prep — x transpose to fp16 + weight conversion (R10 exact).
// ---------------------------------------------------------------------------
__global__ __launch_bounds__(256)
void prep_kernel(const float* __restrict__ x,
                 const float* __restrict__ tw, const float* __restrict__ pw,
                 const float* __restrict__ gw, const float* __restrict__ ww,
                 unsigned short* __restrict__ ws16) {
  const int L = blockIdx.x;            // 1024 = b(4) x nt(64) x ct(4)
  const int b = L >> 8, rem = L & 255, nt = rem >> 2, ct = rem & 3;
  const int n0 = nt * 64, c0 = ct * 64;
  __shared__ unsigned short T[64][68];
  const int tid = threadIdx.x;
  const int tn = (tid & 15) * 4, tc = tid >> 4;

  #pragma unroll
  for (int it = 0; it < 4; ++it) {
    const int c = it*16 + tc;
    float4v v = *(const float4v*)(x + (((size_t)(b*256 + c0 + c)) << 12) + n0 + tn);
    #pragma unroll
    for (int k = 0; k < 4; ++k) T[tn + k][c] = f2h(v[k]);
  }

  if (L < 128) {    // weight conversion fold
    int i = L*1024 + tid*4;
    const float* src; unsigned short* dst; float sc = 1.0f;
    if (i < 32768)      { src = tw + i;           dst = ws16 + WH + i; sc = LOG2E; }
    else if (i < 65536) { src = pw + (i - 32768); dst = ws16 + WH + i; }
    else if (i < 98304) { src = gw + (i - 65536); dst = ws16 + WH + i; }
    else                { src = ww + (i - 98304); dst = ws16 + WOH + (i - 98304); }
    float4v v = *(const float4v*)src;
    us4 o;
    #pragma unroll
    for (int k = 0; k < 4; ++k) o[k] = f2h(v[k] * sc);
    *(us4*)dst = o;
  }
  __syncthreads();

  const int wn = tid >> 4, wc = (tid & 15) * 4;
  #pragma unroll
  for (int it = 0; it < 4; ++it) {
    const int n = it*16 + wn;
    us4 o;
    #pragma unroll
    for (int k = 0; k < 4; ++k) o[k] = T[n][wc + k];
    *(us4*)(ws16 + XH + (((size_t)(b*4096 + n0 + n)) << 8) + c0 + wc) = o;
  }
}

// ---------------------------------------------------------------------------
// Kernel 1: projections via MFMA, no LDS (R10 exact).
// ---------------------------------------------------------------------------
__global__ __launch_bounds__(256)
void proj_kernel(const float* __restrict__ tb, const float* __restrict__ pb,
                 const float* __restrict__ gb, unsigned short* __restrict__ ws16) {
  const int L = blockIdx.x;          // 384
  const int p = L >> 7;              // 0=K,1=V,2=Q
  const int rem = L & 127;
  const int b = rem & 3, nt = rem >> 2;
  const int n0 = nt * 128;
  const int tid = threadIdx.x, w = tid >> 6, lane = tid & 63;
  const int l31 = lane & 31, g = lane >> 5;

  const unsigned short* xrow =
      ws16 + XH + (((size_t)(b*4096 + n0 + w*32 + l31)) << 8) + g*8;
  const unsigned short* wbase = ws16 + WH + (size_t)p*32768 + g*8;

  f32x16 acc[4];
  #pragma unroll
  for (int ot = 0; ot < 4; ++ot) acc[ot] = zero16();

  if (p < 2) {
    #pragma unroll
    for (int kt = 0; kt < 16; ++kt) {
      half8 xf = *(const half8*)(xrow + kt*16);
      #pragma unroll
      for (int ot = 0; ot < 4; ++ot) {
        half8 wf = *(const half8*)(wbase + (((size_t)(ot*32 + l31)) << 8) + kt*16);
        acc[ot] = mfmaf16(xf, wf, acc[ot]);   // D[n][o]
      }
    }
    if (p == 0) {
      unsigned short* outb = ws16 + KT + (((size_t)(b*4096 + n0 + w*32)) << 7);
      #pragma unroll
      for (int ot = 0; ot < 4; ++ot) {
        float bv = tb[ot*32 + l31] * LOG2E;
        #pragma unroll
        for (int r = 0; r < 16; ++r) {
          int row = (r & 3) + 8*(r >> 2) + 4*g;
          outb[(((size_t)row) << 7) + ot*32 + l31] = f2h(acc[ot][r] + bv);
        }
      }
    } else {
      unsigned short* vt = ws16 + VT;
      const size_t mtb = (size_t)(b*128 + nt*4 + w) * 512;
      #pragma unroll
      for (int ot = 0; ot < 4; ++ot) {
        const int o = ot*32 + l31;
        float bv = pb[o];
        const size_t obase = (mtb + (o >> 3)*32)*8 + (o & 7);
        #pragma unroll
        for (int r = 0; r < 16; ++r) {
          int crow = (r & 3) + 8*(r >> 2) + 4*g;
          vt[obase + crow*8] = f2h(acc[ot][r] + bv);
        }
      }
    }
  } else {
    #pragma unroll
    for (int kt = 0; kt < 16; ++kt) {
      half8 xf = *(const half8*)(xrow + kt*16);
      #pragma unroll
      for (int ot = 0; ot < 4; ++ot) {
        half8 wf = *(const half8*)(wbase + (((size_t)(ot*32 + l31)) << 8) + kt*16);
        acc[ot] = mfmaf16(wf, xf, acc[ot]);   // D[o][n]
      }
    }
    unsigned short* qt = ws16 + QT;
    const size_t mtb = (size_t)(b*128 + nt*4 + w) * 512;
    const size_t lbase = (mtb + (l31 >> 3)*128)*8 + (l31 & 7);
    #pragma unroll
    for (int ot = 0; ot < 4; ++ot) {
      #pragma unroll
      for (int r = 0; r < 16; ++r) {
        int o = ot*32 + (r & 3) + 8*(r >> 2) + 4*g;
        qt[lbase + o*8] = f2h(acc[ot][r] + gb[o]);
      }
    }
  }
}

// ---------------------------------------------------------------------------
// Kernel 2: flash attention — LDS-shared tiles (traffic /4) with T3/T4
// counted-vmcnt pipeline: 3 buffers, stage t+2 at iter-t start, end-of-iter
// s_waitcnt vmcnt(4) + RAW s_barrier (loads stay in flight across barrier).
// 4 waves x 32 rows; m-split x4. Grid 512 x 256 thr; LDS 48 KB; 2 blocks/CU.
// ---------------------------------------------------------------------------
__global__ __launch_bounds__(256, 2)
void attn_kernel(unsigned short* __restrict__ ws16,
                 float* __restrict__ Mst, float* __restrict__ Lst) {
  const int L  = blockIdx.x;            // 512
  const int b  = L & 3;
  const int mh = (L >> 2) & 3;
  const int rb = L >> 4;
  const int r0 = rb * 128;
  constexpr int NT = 32;
  const int mt0 = b*128 + mh*32;

  const int tid  = threadIdx.x;
  const int w    = tid >> 6;
  const int lane = tid & 63;
  const int l31  = lane & 31;
  const int g    = lane >> 5;

  __shared__ __align__(16) unsigned char smem[49152];  // 3 x (V 8K | Q 8K)

  const int nrow = r0 + w*32 + l31;
  half8 kh[8];
  {
    const unsigned short* Kt = ws16 + KT + (((size_t)(b*4096 + nrow)) << 7);
    #pragma unroll
    for (int kt = 0; kt < 8; ++kt)
      kh[kt] = *(const half8*)(Kt + kt*16 + g*8);
  }

  f32x16 acc[4];
  #pragma unroll
  for (int ot = 0; ot < 4; ++ot) acc[ot] = zero16();
  float mreg = -INFINITY, lreg = 0.0f;

  const unsigned short* vbase = ws16 + VT + (size_t)mt0*4096;
  const unsigned short* qbase = ws16 + QT + (size_t)mt0*4096;

  // stage tile tt into buffer bi (4 DMA loads per thread: 2 V + 2 Q)
  auto STAGE = [&](int bi, int tt) {
    unsigned char* dst = smem + bi*16384;
    const unsigned short* vs = vbase + (size_t)tt*4096;
    const unsigned short* qs = qbase + (size_t)tt*4096;
    gload16(vs + tid*8,           dst + tid*16);
    gload16(vs + (tid + 256)*8,   dst + (tid + 256)*16);
    gload16(qs + tid*8,           dst + 8192 + tid*16);
    gload16(qs + (tid + 256)*8,   dst + 8192 + (tid + 256)*16);
  };

  // prologue: tiles 0,1 staged; wait own tile-0 writes (tile-1's 4 in flight)
  STAGE(0, 0);
  STAGE(1, 1);
  asm volatile("s_waitcnt vmcnt(4)" ::: "memory");
  __builtin_amdgcn_s_barrier();
  __builtin_amdgcn_sched_barrier(0);

  #pragma unroll 1
  for (int t = 0; t < NT; ++t) {
    unsigned char* vb = smem + (t % 3)*16384;
    unsigned char* qb = vb + 8192;

    if (t + 2 < NT) STAGE((t + 2) % 3, t + 2);   // buf last read at t-1

    // ---- QK^T (log2 domain): two independent 4-deep chains ----
    f32x16 cE = zero16(), cO = zero16();
    __builtin_amdgcn_s_setprio(1);
    #pragma unroll
    for (int j = 0; j < 4; ++j) {
      half8 v0 = *(const half8*)(vb + (((2*j)*2   + g)*32 + l31)*16);
      half8 v1 = *(const half8*)(vb + (((2*j+1)*2 + g)*32 + l31)*16);
      cE = mfmaf16(v0, kh[2*j],   cE);
      cO = mfmaf16(v1, kh[2*j+1], cO);
    }
    __builtin_amdgcn_s_setprio(0);
    f32x16 c0 = cE + cO;

    // ---- softmax: lane owns row n=l31, tree reduce + cross-half shfl ----
    float a4[8];
    #pragma unroll
    for (int i = 0; i < 8; ++i) a4[i] = fmaxf(c0[i], c0[i+8]);
    #pragma unroll
    for (int i = 0; i < 4; ++i) a4[i] = fmaxf(a4[i], a4[i+4]);
    float tm = fmaxf(fmaxf(a4[0], a4[1]), fmaxf(a4[2], a4[3]));
    tm = fmaxf(tm, __shfl_xor(tm, 32));

    float f = 1.0f;
    if (__any(tm > mreg + 11.0f)) {       // T13 defer-max (log2 units)
      float mn = fmaxf(mreg, tm);
      f = ex2(mreg - mn);
      mreg = mn;
      #pragma unroll
      for (int r = 0; r < 16; ++r) {
        const int nl = (r & 3) + 8*(r >> 2) + 4*g;
        float fr = __shfl(f, nl);
        acc[0][r] *= fr; acc[1][r] *= fr; acc[2][r] *= fr; acc[3][r] *= fr;
      }
    }
    #pragma unroll
    for (int r = 0; r < 16; ++r) c0[r] = ex2(c0[r] - mreg);
    float sm[8];
    #pragma unroll
    for (int i = 0; i < 8; ++i) sm[i] = c0[i] + c0[i+8];
    #pragma unroll
    for (int i = 0; i < 4; ++i) sm[i] += sm[i+4];
    float ts = (sm[0] + sm[1]) + (sm[2] + sm[3]);
    ts += __shfl_xor(ts, 32);
    lreg = lreg * f + ts;

    // ---- P -> A-fragments (in-register) ----
    half8 pfr0 = pfrag2(c0[0],c0[1],c0[2],c0[3],c0[4],c0[5],c0[6],c0[7]);
    half8 pfr1 = pfrag2(c0[8],c0[9],c0[10],c0[11],c0[12],c0[13],c0[14],c0[15]);

    // ---- PV from LDS Q fragments ----
    __builtin_amdgcn_s_setprio(1);
    #pragma unroll
    for (int ot = 0; ot < 4; ++ot) {
      half8 qf0 = *(const half8*)(qb + ((0*2 + g)*128 + ot*32 + l31)*16);
      half8 qf1 = *(const half8*)(qb + ((1*2 + g)*128 + ot*32 + l31)*16);
      acc[ot] = mfmaf16(pfr0, qf0, acc[ot]);
      acc[ot] = mfmaf16(pfr1, qf1, acc[ot]);
    }
    __builtin_amdgcn_s_setprio(0);

    // ---- counted drain: tile t+1 landed; t+2's 4 loads stay in flight ----
    if (t + 1 < NT) {
      if (t + 2 < NT) { asm volatile("s_waitcnt vmcnt(4)" ::: "memory"); }
      else            { asm volatile("s_waitcnt vmcnt(0)" ::: "memory"); }
      __builtin_amdgcn_s_barrier();
      __builtin_amdgcn_sched_barrier(0);
    }
  }

  // epilogue: normalized fp16 partial -> OB[mh][b][n][o]
  unsigned short* Ob = ws16 + OB + (size_t)mh*OSZ + (((size_t)(b*4096)) << 7);
  const float linv_own = 1.0f / lreg;
  #pragma unroll
  for (int r = 0; r < 16; ++r) {
    const int nl = (r & 3) + 8*(r >> 2) + 4*g;
    const float linv = __shfl(linv_own, nl);
    const size_t nb = ((size_t)(r0 + w*32 + nl)) << 7;
    #pragma unroll
    for (int ot = 0; ot < 4; ++ot) {
      const int o_ = ot*32 + l31;
      Ob[nb + o_] = f2h(acc[ot][r] * linv);
    }
  }
  if (lane < 32) {
    const int n_ = r0 + w*32 + l31;
    Mst[((mh*4 + b) << 12) + n_] = mreg;   // log2 domain
    Lst[((mh*4 + b) << 12) + n_] = lreg;
  }
}

// ---------------------------------------------------------------------------
// Kernel 3: out projection via MFMA with fused 4-partial merge (R10 exact).
// ---------------------------------------------------------------------------
__global__ __launch_bounds__(256)
void out_kernel(const float* __restrict__ x, const float* __restrict__ wb,
                const unsigned short* __restrict__ ws16,
                const float* __restrict__ Mst, const float* __restrict__ Lst,
                float* __restrict__ out) {
  const int L = blockIdx.x;            // 256
  const int b = L & 3, nt = L >> 2;
  const int n0 = nt * 64;
  const int tid = threadIdx.x, w = tid >> 6, lane = tid & 63;
  const int l31 = lane & 31, g = lane >> 5;
  const int nsub = w & 1, chalf = w >> 1;

  __shared__ float cs[4][64];
  if (tid < 64) {
    const int n_ = n0 + tid;
    float m0 = Mst[((0*4+b) << 12) + n_], l0 = Lst[((0*4+b) << 12) + n_];
    float m1 = Mst[((1*4+b) << 12) + n_], l1 = Lst[((1*4+b) << 12) + n_];
    float m2 = Mst[((2*4+b) << 12) + n_], l2 = Lst[((2*4+b) << 12) + n_];
    float m3 = Mst[((3*4+b) << 12) + n_], l3 = Lst[((3*4+b) << 12) + n_];
    float M = fmaxf(fmaxf(m0, m1), fmaxf(m2, m3));
    float w0 = l0 * exp2f(m0 - M);       // stats are log2-domain
    float w1 = l1 * exp2f(m1 - M);
    float w2 = l2 * exp2f(m2 - M);
    float w3 = l3 * exp2f(m3 - M);
    float inv = 1.0f / (w0 + w1 + w2 + w3);
    cs[0][tid] = w0*inv; cs[1][tid] = w1*inv; cs[2][tid] = w2*inv; cs[3][tid] = w3*inv;
  }
  __syncthreads();

  const int n_lane = n0 + nsub*32 + l31;
  unsigned csh[4];
  #pragma unroll
  for (int p = 0; p < 4; ++p) {
    float c = cs[p][nsub*32 + l31];
    csh[p] = pkf(c, c);
  }

  f32x16 acc[4];
  #pragma unroll
  for (int ct = 0; ct < 4; ++ct) acc[ct] = zero16();

  const unsigned short* ob = ws16 + OB + (((size_t)(b*4096 + n_lane)) << 7) + g*8;
  const unsigned short* wrow = ws16 + WOH + g*8;

  #pragma unroll
  for (int kt = 0; kt < 8; ++kt) {
    uN4 u0 = *(const uN4*)(ob + kt*16);
    uN4 u1 = *(const uN4*)(ob + OSZ + kt*16);
    uN4 u2 = *(const uN4*)(ob + 2*OSZ + kt*16);
    uN4 u3 = *(const uN4*)(ob + 3*OSZ + kt*16);
    union { uN4 u; half8 h; } m;
    #pragma unroll
    for (int i = 0; i < 4; ++i)
      m.u[i] = pkfma(u0[i], csh[0],
               pkfma(u1[i], csh[1],
               pkfma(u2[i], csh[2], pkmul(u3[i], csh[3]))));
    #pragma unroll
    for (int ct = 0; ct < 4; ++ct) {
      half8 wf = *(const half8*)(wrow + (((size_t)((chalf*4 + ct)*32 + l31)) << 7) + kt*16);
      acc[ct] = mfmaf16(wf, m.h, acc[ct]);   // D[c][n]
    }
  }

  #pragma unroll
  for (int ct = 0; ct < 4; ++ct) {
    #pragma unroll
    for (int r = 0; r < 16; ++r) {
      const int c = (chalf*4 + ct)*32 + (r & 3) + 8*(r >> 2) + 4*g;
      const size_t off = ((size_t)(b*256 + c) << 12) + n_lane;
      out[off] = acc[ct][r] + wb[c] + x[off];
    }
  }
}

extern "C" void kernel_launch(void* const* d_in, const int* in_sizes, int n_in,
                              void* d_out, int out_size, void* d_ws, size_t ws_size,
                              hipStream_t stream) {
  const float* x  = (const float*)d_in[0];
  const float* tw = (const float*)d_in[1];
  const float* tb = (const float*)d_in[2];
  const float* pw = (const float*)d_in[3];
  const float* pb = (const float*)d_in[4];
  const float* gw = (const float*)d_in[5];
  const float* gb = (const float*)d_in[6];
  const float* ww = (const float*)d_in[7];
  const float* wbb= (const float*)d_in[8];

  unsigned short* ws16 = (unsigned short*)d_ws;
  float* Mst = (float*)((char*)d_ws + STAT_BYTE);
  float* Lst = Mst + 16*4096;
  float* out = (float*)d_out;

  if (ws_size < 33554432u) return;

  prep_kernel<<<1024, 256, 0, stream>>>(x, tw, pw, gw, ww, ws16);
  proj_kernel<<<384, 256, 0, stream>>>(tb, pb, gb, ws16);
  attn_kernel<<<512, 256, 0, stream>>>(ws16, Mst, Lst);
  out_kernel<<<256, 256, 0, stream>>>(x, wbb, ws16, Mst, Lst, out);
}

// Round 14
// 92.595 us; speedup vs baseline: 1.2366x; 1.0374x over previous
//
#include <hip/hip_runtime.h>
#include <hip/hip_bf16.h>
#include <math.h>

typedef float  float4v __attribute__((ext_vector_type(4)));
typedef float  f32x16  __attribute__((ext_vector_type(16)));
typedef _Float16 half8  __attribute__((ext_vector_type(8)));
typedef _Float16 h2v    __attribute__((ext_vector_type(2)));
typedef __fp16  fp16x2 __attribute__((ext_vector_type(2)));
typedef unsigned int   uN4 __attribute__((ext_vector_type(4)));
typedef unsigned int   uint2v __attribute__((ext_vector_type(2)));
typedef unsigned short us4 __attribute__((ext_vector_type(4)));

constexpr int Cc = 256;    // C_IN
constexpr int Ci = 128;    // C_INT
constexpr int Nn = 4096;   // H*W
constexpr float LOG2E = 1.4426950408889634f;

// ws layout (ushort units). All fp16 unless noted.
// V and Q stored FRAGMENT-TILED (granule = 16B = 8 halves):
//   V_tiled[b][mt(128)][slot(16)= kt*2+g][m_in(32)][e(8)]
//   Q_tiled[b][mt(128)][s(4) = kt2*2+g][o(128)][e(8)]
constexpr size_t KT  = 0;          // K [b][n][o] (4 MB) — log2e-scaled
constexpr size_t VT  = 2097152;    // V tiled (4 MB)
constexpr size_t QT  = 4194304;    // Q tiled (4 MB)
constexpr size_t OB  = 6291456;    // O partials [mh][b][n][o], 4 x 4 MB
constexpr size_t OSZ = 2097152;
constexpr size_t XH  = 6291456;    // x^T [b][n][c] fp16 (8 MB) — ALIASES OB[0..1]
constexpr size_t STAT_BYTE = 29360128;  // Mst[16][4096], Lst[16][4096] f32
constexpr size_t WH  = 14942208;   // stacked weights fp16 [384][256]
constexpr size_t WOH = 15040512;   // w_w fp16 [256][128]

__device__ __forceinline__ f32x16 zero16() {
  f32x16 z;
  #pragma unroll
  for (int r = 0; r < 16; ++r) z[r] = 0.0f;
  return z;
}
__device__ __forceinline__ unsigned pkf(float x, float y) {
  union { fp16x2 h; unsigned u; } c;
  c.h = __builtin_amdgcn_cvt_pkrtz(x, y);
  return c.u;
}
__device__ __forceinline__ f32x16 mfmaf16(half8 a, half8 b, f32x16 c) {
  return __builtin_amdgcn_mfma_f32_32x32x16_f16(a, b, c, 0, 0, 0);
}
__device__ __forceinline__ float h2f(unsigned short u) {
  union { unsigned short u; _Float16 h; } c; c.u = u; return (float)c.h;
}
__device__ __forceinline__ unsigned short f2h(float x) {
  union { _Float16 h; unsigned short u; } c; c.h = (_Float16)x; return c.u;
}
__device__ __forceinline__ unsigned pkfma(unsigned a, unsigned b, unsigned c) {
  union { unsigned u; h2v h; } A, B, C, R;
  A.u = a; B.u = b; C.u = c;
  R.h = A.h * B.h + C.h;
  return R.u;
}
__device__ __forceinline__ unsigned pkmul(unsigned a, unsigned b) {
  union { unsigned u; h2v h; } A, B, R;
  A.u = a; B.u = b;
  R.h = A.h * B.h;
  return R.u;
}
__device__ __forceinline__ float ex2(float x) {
  float r;
  asm volatile("v_exp_f32 %0, %1\n\ts_nop 0" : "=v"(r) : "v"(x));
  return r;
}

// PV A-fragment from this lane's 8 P-values via permlane32_swap (T12).
__device__ __forceinline__ half8 pfrag2(float p0, float p1, float p2, float p3,
                                        float p4, float p5, float p6, float p7) {
  unsigned a0 = pkf(p0, p1), a1 = pkf(p2, p3);
  unsigned b0 = pkf(p4, p5), b1 = pkf(p6, p7);
  uint2v rA = __builtin_amdgcn_permlane32_swap(a0, b0, false, false);
  uint2v rB = __builtin_amdgcn_permlane32_swap(a1, b1, false, false);
  union { unsigned u[4]; half8 h; } r;
  r.u[0] = rA.x; r.u[1] = rB.x; r.u[2] = rA.y; r.u[3] = rB.y;
  return r.h;
}

// ---------------------------------------------------------------------------
// Kernel 0: prep — x transpose to fp16 + weight conversion (R10 exact).
// ---------------------------------------------------------------------------
__global__ __launch_bounds__(256)
void prep_kernel(const float* __restrict__ x,
                 const float* __restrict__ tw, const float* __restrict__ pw,
                 const float* __restrict__ gw, const float* __restrict__ ww,
                 unsigned short* __restrict__ ws16) {
  const int L = blockIdx.x;            // 1024 = b(4) x nt(64) x ct(4)
  const int b = L >> 8, rem = L & 255, nt = rem >> 2, ct = rem & 3;
  const int n0 = nt * 64, c0 = ct * 64;
  __shared__ unsigned short T[64][68];
  const int tid = threadIdx.x;
  const int tn = (tid & 15) * 4, tc = tid >> 4;

  #pragma unroll
  for (int it = 0; it < 4; ++it) {
    const int c = it*16 + tc;
    float4v v = *(const float4v*)(x + (((size_t)(b*256 + c0 + c)) << 12) + n0 + tn);
    #pragma unroll
    for (int k = 0; k < 4; ++k) T[tn + k][c] = f2h(v[k]);
  }

  if (L < 128) {    // weight conversion fold
    int i = L*1024 + tid*4;
    const float* src; unsigned short* dst; float sc = 1.0f;
    if (i < 32768)      { src = tw + i;           dst = ws16 + WH + i; sc = LOG2E; }
    else if (i < 65536) { src = pw + (i - 32768); dst = ws16 + WH + i; }
    else if (i < 98304) { src = gw + (i - 65536); dst = ws16 + WH + i; }
    else                { src = ww + (i - 98304); dst = ws16 + WOH + (i - 98304); }
    float4v v = *(const float4v*)src;
    us4 o;
    #pragma unroll
    for (int k = 0; k < 4; ++k) o[k] = f2h(v[k] * sc);
    *(us4*)dst = o;
  }
  __syncthreads();

  const int wn = tid >> 4, wc = (tid & 15) * 4;
  #pragma unroll
  for (int it = 0; it < 4; ++it) {
    const int n = it*16 + wn;
    us4 o;
    #pragma unroll
    for (int k = 0; k < 4; ++k) o[k] = T[n][wc + k];
    *(us4*)(ws16 + XH + (((size_t)(b*4096 + n0 + n)) << 8) + c0 + wc) = o;
  }
}

// ---------------------------------------------------------------------------
// Kernel 1: projections via MFMA, no LDS. SPLIT o-dim x2 for occupancy:
// 768 blocks = p(3) x oh(2) x nt(32) x b(4); 256 thr; each wave 2 chains.
// ---------------------------------------------------------------------------
__global__ __launch_bounds__(256)
void proj_kernel(const float* __restrict__ tb, const float* __restrict__ pb,
                 const float* __restrict__ gb, unsigned short* __restrict__ ws16) {
  const int L = blockIdx.x;          // 768
  const int p = L >> 8;              // 0=K,1=V,2=Q
  const int rem = L & 255;
  const int b = rem & 3, nt = (rem >> 2) & 31, oh = rem >> 7;
  const int n0 = nt * 128;
  const int tid = threadIdx.x, w = tid >> 6, lane = tid & 63;
  const int l31 = lane & 31, g = lane >> 5;

  const unsigned short* xrow =
      ws16 + XH + (((size_t)(b*4096 + n0 + w*32 + l31)) << 8) + g*8;
  const unsigned short* wbase = ws16 + WH + (size_t)p*32768 + g*8;

  f32x16 acc[2];
  acc[0] = zero16(); acc[1] = zero16();

  if (p < 2) {
    #pragma unroll
    for (int kt = 0; kt < 16; ++kt) {
      half8 xf = *(const half8*)(xrow + kt*16);
      #pragma unroll
      for (int j = 0; j < 2; ++j) {
        const int o = (oh*2 + j)*32 + l31;
        half8 wf = *(const half8*)(wbase + (((size_t)o) << 8) + kt*16);
        acc[j] = mfmaf16(xf, wf, acc[j]);   // D[n][o]
      }
    }
    if (p == 0) {
      unsigned short* outb = ws16 + KT + (((size_t)(b*4096 + n0 + w*32)) << 7);
      #pragma unroll
      for (int j = 0; j < 2; ++j) {
        const int o = (oh*2 + j)*32 + l31;
        float bv = tb[o] * LOG2E;
        #pragma unroll
        for (int r = 0; r < 16; ++r) {
          int row = (r & 3) + 8*(r >> 2) + 4*g;
          outb[(((size_t)row) << 7) + o] = f2h(acc[j][r] + bv);
        }
      }
    } else {
      unsigned short* vt = ws16 + VT;
      const size_t mtb = (size_t)(b*128 + nt*4 + w) * 512;
      #pragma unroll
      for (int j = 0; j < 2; ++j) {
        const int o = (oh*2 + j)*32 + l31;
        float bv = pb[o];
        const size_t obase = (mtb + (o >> 3)*32)*8 + (o & 7);
        #pragma unroll
        for (int r = 0; r < 16; ++r) {
          int crow = (r & 3) + 8*(r >> 2) + 4*g;
          vt[obase + crow*8] = f2h(acc[j][r] + bv);
        }
      }
    }
  } else {
    #pragma unroll
    for (int kt = 0; kt < 16; ++kt) {
      half8 xf = *(const half8*)(xrow + kt*16);
      #pragma unroll
      for (int j = 0; j < 2; ++j) {
        const int o = (oh*2 + j)*32 + l31;
        half8 wf = *(const half8*)(wbase + (((size_t)o) << 8) + kt*16);
        acc[j] = mfmaf16(wf, xf, acc[j]);   // D[o][n]
      }
    }
    unsigned short* qt = ws16 + QT;
    const size_t mtb = (size_t)(b*128 + nt*4 + w) * 512;
    const size_t lbase = (mtb + (l31 >> 3)*128)*8 + (l31 & 7);
    #pragma unroll
    for (int j = 0; j < 2; ++j) {
      #pragma unroll
      for (int r = 0; r < 16; ++r) {
        int o = (oh*2 + j)*32 + (r & 3) + 8*(r >> 2) + 4*g;
        qt[lbase + o*8] = f2h(acc[j][r] + gb[o]);
      }
    }
  }
}

// ---------------------------------------------------------------------------
// Kernel 2: flash attention — R10 exact structure, s_setprio REMOVED (A/B).
// No LDS/barriers; register single-buffer rotation, counted implicit waits.
// ---------------------------------------------------------------------------
__global__ __launch_bounds__(256, 2)
void attn_kernel(unsigned short* __restrict__ ws16,
                 float* __restrict__ Mst, float* __restrict__ Lst) {
  const int L  = blockIdx.x;            // 512
  const int b  = L & 3;
  const int mh = (L >> 2) & 3;
  const int rb = L >> 4;
  const int r0 = rb * 128;
  constexpr int NT = 32;
  const int mt0 = b*128 + mh*32;

  const int tid  = threadIdx.x;
  const int w    = tid >> 6;
  const int lane = tid & 63;
  const int l31  = lane & 31;
  const int g    = lane >> 5;

  const int nrow = r0 + w*32 + l31;
  half8 kh[8];
  {
    const unsigned short* Kt = ws16 + KT + (((size_t)(b*4096 + nrow)) << 7);
    #pragma unroll
    for (int kt = 0; kt < 8; ++kt)
      kh[kt] = *(const half8*)(Kt + kt*16 + g*8);
  }

  f32x16 acc[4];
  #pragma unroll
  for (int ot = 0; ot < 4; ++ot) acc[ot] = zero16();
  float mreg = -INFINITY, lreg = 0.0f;

  const unsigned short* vbase = ws16 + VT + (size_t)mt0*4096;
  const unsigned short* qbase = ws16 + QT + (size_t)mt0*4096;

  half8 vbuf[8], qbuf[8];
  #pragma unroll
  for (int kt = 0; kt < 8; ++kt)
    vbuf[kt] = *(const half8*)(vbase + ((kt*2 + g)*32 + l31)*8);
  #pragma unroll
  for (int ot = 0; ot < 4; ++ot) {
    qbuf[ot*2+0] = *(const half8*)(qbase + ((0*2 + g)*128 + ot*32 + l31)*8);
    qbuf[ot*2+1] = *(const half8*)(qbase + ((1*2 + g)*128 + ot*32 + l31)*8);
  }

  #pragma unroll 1
  for (int t = 0; t < NT; ++t) {
    const size_t tn = (size_t)((t + 1) & 31);   // last-iter wrap (in-bounds, unused)

    // ---- QK^T (log2 domain): two independent 4-deep chains ----
    f32x16 cE = zero16(), cO = zero16();
    #pragma unroll
    for (int kt = 0; kt < 4; ++kt) {
      cE = mfmaf16(vbuf[2*kt],   kh[2*kt],   cE);
      cO = mfmaf16(vbuf[2*kt+1], kh[2*kt+1], cO);
    }
    f32x16 c0 = cE + cO;

    // ---- overwrite vbuf with V(t+1): next use is a full softmax+PV away ----
    {
      const unsigned short* vs = vbase + tn*4096;
      #pragma unroll
      for (int kt = 0; kt < 8; ++kt)
        vbuf[kt] = *(const half8*)(vs + ((kt*2 + g)*32 + l31)*8);
    }

    // ---- softmax: lane owns row n=l31, tree reduce + cross-half shfl ----
    float a4[8];
    #pragma unroll
    for (int i = 0; i < 8; ++i) a4[i] = fmaxf(c0[i], c0[i+8]);
    #pragma unroll
    for (int i = 0; i < 4; ++i) a4[i] = fmaxf(a4[i], a4[i+4]);
    float tm = fmaxf(fmaxf(a4[0], a4[1]), fmaxf(a4[2], a4[3]));
    tm = fmaxf(tm, __shfl_xor(tm, 32));

    float f = 1.0f;
    if (__any(tm > mreg + 11.0f)) {       // T13 defer-max (log2 units)
      float mn = fmaxf(mreg, tm);
      f = ex2(mreg - mn);
      mreg = mn;
      #pragma unroll
      for (int r = 0; r < 16; ++r) {
        const int nl = (r & 3) + 8*(r >> 2) + 4*g;
        float fr = __shfl(f, nl);
        acc[0][r] *= fr; acc[1][r] *= fr; acc[2][r] *= fr; acc[3][r] *= fr;
      }
    }
    #pragma unroll
    for (int r = 0; r < 16; ++r) c0[r] = ex2(c0[r] - mreg);
    float sm[8];
    #pragma unroll
    for (int i = 0; i < 8; ++i) sm[i] = c0[i] + c0[i+8];
    #pragma unroll
    for (int i = 0; i < 4; ++i) sm[i] += sm[i+4];
    float ts = (sm[0] + sm[1]) + (sm[2] + sm[3]);
    ts += __shfl_xor(ts, 32);
    lreg = lreg * f + ts;

    // ---- P -> A-fragments (in-register) ----
    half8 pfr0 = pfrag2(c0[0],c0[1],c0[2],c0[3],c0[4],c0[5],c0[6],c0[7]);
    half8 pfr1 = pfrag2(c0[8],c0[9],c0[10],c0[11],c0[12],c0[13],c0[14],c0[15]);

    // ---- PV from qbuf regs (loaded one iteration ago) ----
    #pragma unroll
    for (int ot = 0; ot < 4; ++ot) {
      acc[ot] = mfmaf16(pfr0, qbuf[ot*2+0], acc[ot]);
      acc[ot] = mfmaf16(pfr1, qbuf[ot*2+1], acc[ot]);
    }

    // ---- overwrite qbuf with Q(t+1): next use is QK^T+softmax away ----
    {
      const unsigned short* qs = qbase + tn*4096;
      #pragma unroll
      for (int ot = 0; ot < 4; ++ot) {
        qbuf[ot*2+0] = *(const half8*)(qs + ((0*2 + g)*128 + ot*32 + l31)*8);
        qbuf[ot*2+1] = *(const half8*)(qs + ((1*2 + g)*128 + ot*32 + l31)*8);
      }
    }
  }

  // epilogue: normalized fp16 partial -> OB[mh][b][n][o]
  unsigned short* Ob = ws16 + OB + (size_t)mh*OSZ + (((size_t)(b*4096)) << 7);
  const float linv_own = 1.0f / lreg;
  #pragma unroll
  for (int r = 0; r < 16; ++r) {
    const int nl = (r & 3) + 8*(r >> 2) + 4*g;
    const float linv = __shfl(linv_own, nl);
    const size_t nb = ((size_t)(r0 + w*32 + nl)) << 7;
    #pragma unroll
    for (int ot = 0; ot < 4; ++ot) {
      const int o_ = ot*32 + l31;
      Ob[nb + o_] = f2h(acc[ot][r] * linv);
    }
  }
  if (lane < 32) {
    const int n_ = r0 + w*32 + l31;
    Mst[((mh*4 + b) << 12) + n_] = mreg;   // log2 domain
    Lst[((mh*4 + b) << 12) + n_] = lreg;
  }
}

// ---------------------------------------------------------------------------
// Kernel 3: out projection — SPLIT c-dim x2 for occupancy: 512 blocks =
// ch(1) x nt(64) x b(4) x 2; each block 128 c x 64 n; each wave 2 chains.
// ---------------------------------------------------------------------------
__global__ __launch_bounds__(256)
void out_kernel(const float* __restrict__ x, const float* __restrict__ wb,
                const unsigned short* __restrict__ ws16,
                const float* __restrict__ Mst, const float* __restrict__ Lst,
                float* __restrict__ out) {
  const int L = blockIdx.x;            // 512
  const int b = L & 3, nt = (L >> 2) & 63, ch = L >> 8;
  const int n0 = nt * 64;
  const int tid = threadIdx.x, w = tid >> 6, lane = tid & 63;
  const int l31 = lane & 31, g = lane >> 5;
  const int nsub = w & 1, chalf = w >> 1;

  __shared__ float cs[4][64];
  if (tid < 64) {
    const int n_ = n0 + tid;
    float m0 = Mst[((0*4+b) << 12) + n_], l0 = Lst[((0*4+b) << 12) + n_];
    float m1 = Mst[((1*4+b) << 12) + n_], l1 = Lst[((1*4+b) << 12) + n_];
    float m2 = Mst[((2*4+b) << 12) + n_], l2 = Lst[((2*4+b) << 12) + n_];
    float m3 = Mst[((3*4+b) << 12) + n_], l3 = Lst[((3*4+b) << 12) + n_];
    float M = fmaxf(fmaxf(m0, m1), fmaxf(m2, m3));
    float w0 = l0 * exp2f(m0 - M);       // stats are log2-domain
    float w1 = l1 * exp2f(m1 - M);
    float w2 = l2 * exp2f(m2 - M);
    float w3 = l3 * exp2f(m3 - M);
    float inv = 1.0f / (w0 + w1 + w2 + w3);
    cs[0][tid] = w0*inv; cs[1][tid] = w1*inv; cs[2][tid] = w2*inv; cs[3][tid] = w3*inv;
  }
  __syncthreads();

  const int n_lane = n0 + nsub*32 + l31;
  unsigned csh[4];
  #pragma unroll
  for (int p = 0; p < 4; ++p) {
    float c = cs[p][nsub*32 + l31];
    csh[p] = pkf(c, c);
  }

  f32x16 acc[2];
  acc[0] = zero16(); acc[1] = zero16();

  const unsigned short* ob = ws16 + OB + (((size_t)(b*4096 + n_lane)) << 7) + g*8;
  const unsigned short* wrow = ws16 + WOH + g*8;

  #pragma unroll
  for (int kt = 0; kt < 8; ++kt) {
    uN4 u0 = *(const uN4*)(ob + kt*16);
    uN4 u1 = *(const uN4*)(ob + OSZ + kt*16);
    uN4 u2 = *(const uN4*)(ob + 2*OSZ + kt*16);
    uN4 u3 = *(const uN4*)(ob + 3*OSZ + kt*16);
    union { uN4 u; half8 h; } m;
    #pragma unroll
    for (int i = 0; i < 4; ++i)
      m.u[i] = pkfma(u0[i], csh[0],
               pkfma(u1[i], csh[1],
               pkfma(u2[i], csh[2], pkmul(u3[i], csh[3]))));
    #pragma unroll
    for (int ct = 0; ct < 2; ++ct) {
      const int crow32 = ch*4 + chalf*2 + ct;          // 32-row group of w_w
      half8 wf = *(const half8*)(wrow + (((size_t)(crow32*32 + l31)) << 7) + kt*16);
      acc[ct] = mfmaf16(wf, m.h, acc[ct]);   // D[c][n]
    }
  }

  #pragma unroll
  for (int ct = 0; ct < 2; ++ct) {
    const int crow32 = ch*4 + chalf*2 + ct;
    #pragma unroll
    for (int r = 0; r < 16; ++r) {
      const int c = crow32*32 + (r & 3) + 8*(r >> 2) + 4*g;
      const size_t off = ((size_t)(b*256 + c) << 12) + n_lane;
      out[off] = acc[ct][r] + wb[c] + x[off];
    }
  }
}

extern "C" void kernel_launch(void* const* d_in, const int* in_sizes, int n_in,
                              void* d_out, int out_size, void* d_ws, size_t ws_size,
                              hipStream_t stream) {
  const float* x  = (const float*)d_in[0];
  const float* tw = (const float*)d_in[1];
  const float* tb = (const float*)d_in[2];
  const float* pw = (const float*)d_in[3];
  const float* pb = (const float*)d_in[4];
  const float* gw = (const float*)d_in[5];
  const float* gb = (const float*)d_in[6];
  const float* ww = (const float*)d_in[7];
  const float* wbb= (const float*)d_in[8];

  unsigned short* ws16 = (unsigned short*)d_ws;
  float* Mst = (float*)((char*)d_ws + STAT_BYTE);
  float* Lst = Mst + 16*4096;
  float* out = (float*)d_out;

  if (ws_size < 33554432u) return;

  prep_kernel<<<1024, 256, 0, stream>>>(x, tw, pw, gw, ww, ws16);
  proj_kernel<<<768, 256, 0, stream>>>(tb, pb, gb, ws16);
  attn_kernel<<<512, 256, 0, stream>>>(ws16, Mst, Lst);
  out_kernel<<<512, 256, 0, stream>>>(x, wbb, ws16, Mst, Lst, out);
}